// Round 6
// baseline (593.765 us; speedup 1.0000x reference)
//
#include <hip/hip_runtime.h>
#include <cstdint>

namespace {

constexpr int kB = 1024;
constexpr int kF = 12;
constexpr int kD = 512;
constexpr int kNT = kB * kD;        // 524288

// ---------------- threefry2x32 (exact JAX semantics) ----------------
#define TF_ROUND(r) { x0 += x1; x1 = (x1 << (r)) | (x1 >> (32 - (r))); x1 ^= x0; }

__host__ __device__ inline void tf2x32(uint32_t k0, uint32_t k1,
                                       uint32_t c0, uint32_t c1,
                                       uint32_t& o0, uint32_t& o1) {
  uint32_t ks2 = k0 ^ k1 ^ 0x1BD11BDAu;
  uint32_t x0 = c0 + k0;
  uint32_t x1 = c1 + k1;
  TF_ROUND(13) TF_ROUND(15) TF_ROUND(26) TF_ROUND(6)
  x0 += k1;  x1 += ks2 + 1u;
  TF_ROUND(17) TF_ROUND(29) TF_ROUND(16) TF_ROUND(24)
  x0 += ks2; x1 += k0 + 2u;
  TF_ROUND(13) TF_ROUND(15) TF_ROUND(26) TF_ROUND(6)
  x0 += k0;  x1 += k1 + 3u;
  TF_ROUND(17) TF_ROUND(29) TF_ROUND(16) TF_ROUND(24)
  x0 += k1;  x1 += ks2 + 4u;
  TF_ROUND(13) TF_ROUND(15) TF_ROUND(26) TF_ROUND(6)
  x0 += ks2; x1 += k0 + 5u;
  o0 = x0; o1 = x1;
}

// Device cipher specialized for counter (0, i); rotates fuse to v_alignbit.
// Returns x0 ^ x1 (JAX partitionable random_bits word).
__device__ __forceinline__ uint32_t rbits0(uint32_t k0, uint32_t k1,
                                           uint32_t ks2, uint32_t i) {
#define RR(r) { x0 += x1; x1 = __builtin_rotateleft32(x1, r); x1 ^= x0; }
  uint32_t x0 = k0;
  uint32_t x1 = i + k1;
  RR(13) RR(15) RR(26) RR(6)
  x0 += k1;  x1 += ks2 + 1u;
  RR(17) RR(29) RR(16) RR(24)
  x0 += ks2; x1 += k0 + 2u;
  RR(13) RR(15) RR(26) RR(6)
  x0 += k0;  x1 += k1 + 3u;
  RR(17) RR(29) RR(16) RR(24)
  x0 += k1;  x1 += ks2 + 4u;
  RR(13) RR(15) RR(26) RR(6)
  x0 += ks2; x1 += k0 + 5u;
  return x0 ^ x1;
#undef RR
}

// ---------------- fast HW transcendentals ----------------
__device__ __forceinline__ float fast_log2(float x) {
#if __has_builtin(__builtin_amdgcn_logf)
  return __builtin_amdgcn_logf(x);
#else
  return __log2f(x);
#endif
}

__device__ __forceinline__ float fast_sqrt(float x) {
#if __has_builtin(__builtin_amdgcn_sqrtf)
  return __builtin_amdgcn_sqrtf(x);
#else
  return sqrtf(x);
#endif
}

// 1/sqrt(x) via v_rsq + one Newton step (rel err ~1e-7)
__device__ __forceinline__ float rsq_nr(float x) {
#if __has_builtin(__builtin_amdgcn_rsqf)
  float r = __builtin_amdgcn_rsqf(x);
#else
  float r = 1.0f / sqrtf(x);
#endif
  float h = 0.5f * x;
  return r * (1.5f - h * r * r);
}

// p*u where sqrt(2)*p*u = sqrt(2)*erfinv(u), u from JAX-normal bit recipe.
// Head trimmed: u = fma(cvt(bits>>9), 2^-22, lo) is bit-identical to the
// (|0x3F800000)-1.0, *2+lo, fmax sequence (x*2^-23 exact, Sterbenz, fmax
// redundant since round(s>=lo) >= lo). Tail poly behind wave-uniform branch.
__device__ __forceinline__ float normpx(uint32_t bits) {
  const float lo = __uint_as_float(0xBF7FFFFFu);                 // -0.99999994
  float u = fmaf((float)(bits >> 9), 0x1p-22f, lo);
  float y = fmaf(-u, u, 1.0f);                                   // 1-u^2
  float w = -0.69314718055994531f * fast_log2(y);                // -ln(1-u^2)
  float wa = w - 2.5f;
  float p = 2.81022636e-08f;
  p = fmaf(p, wa, 3.43273939e-07f);
  p = fmaf(p, wa, -3.5233877e-06f);
  p = fmaf(p, wa, -4.39150654e-06f);
  p = fmaf(p, wa, 0.00021858087f);
  p = fmaf(p, wa, -0.00125372503f);
  p = fmaf(p, wa, -0.00417768164f);
  p = fmaf(p, wa, 0.246640727f);
  p = fmaf(p, wa, 1.50140941f);
  if (__builtin_expect(__any(w >= 5.0f), 0)) {
    float wb = fast_sqrt(w) - 3.0f;
    float pb = -0.000200214257f;
    pb = fmaf(pb, wb, 0.000100950558f);
    pb = fmaf(pb, wb, 0.00134934322f);
    pb = fmaf(pb, wb, -0.00367342844f);
    pb = fmaf(pb, wb, 0.00573950773f);
    pb = fmaf(pb, wb, -0.0076224613f);
    pb = fmaf(pb, wb, 0.00943887047f);
    pb = fmaf(pb, wb, 1.00167406f);
    pb = fmaf(pb, wb, 2.83297682f);
    p = (w < 5.0f) ? p : pb;
  }
  return p * u;
}

// 5-level xor-butterfly within 32-lane groups via raw ds_swizzle (BitMode:
// offset = (xor_mask<<10) | 0x1F). Zero VALU for the lane move.
__device__ __forceinline__ float swz_add(float x) {
  x += __int_as_float(__builtin_amdgcn_ds_swizzle(__float_as_int(x), 0x041F));
  x += __int_as_float(__builtin_amdgcn_ds_swizzle(__float_as_int(x), 0x081F));
  x += __int_as_float(__builtin_amdgcn_ds_swizzle(__float_as_int(x), 0x101F));
  x += __int_as_float(__builtin_amdgcn_ds_swizzle(__float_as_int(x), 0x201F));
  x += __int_as_float(__builtin_amdgcn_ds_swizzle(__float_as_int(x), 0x401F));
  return x;
}

// ---------------- block reductions for loss1 kernels ----------------
__device__ __forceinline__ float breduce(float x, float* s4) {
#pragma unroll
  for (int o = 32; o; o >>= 1) x += __shfl_xor(x, o);
  const int w = threadIdx.x >> 6;
  if ((threadIdx.x & 63) == 0) s4[w] = x;
  __syncthreads();
  float r = s4[0] + s4[1] + s4[2] + s4[3];
  __syncthreads();
  return r;
}

struct KeyChain { uint32_t k[120]; };  // per step: kv0,kv1,kt0,kt1

// ---------------- loss1 kernels ----------------
__global__ __launch_bounds__(256) void k_vidmean(const float* __restrict__ vid,
                                                 float* __restrict__ vm) {
  __shared__ float s4[4];
  const int b = blockIdx.x, tid = threadIdx.x;
  float a0 = 0.f, a1 = 0.f;
  for (int f = 0; f < kF; ++f) {
    const float* row = vid + (b * kF + f) * kD;
    float x0 = row[tid], x1 = row[tid + 256];
    float nn = breduce(x0 * x0 + x1 * x1, s4);
    float n = fmaxf(sqrtf(nn), 1e-12f);
    a0 += x0 / n;
    a1 += x1 / n;
  }
  vm[b * kD + tid] = a0 / 12.0f;
  vm[b * kD + tid + 256] = a1 / 12.0f;
}

// txt row-normalize + paired diag dot with vm (fused k_txtnorm + k_pos)
__global__ __launch_bounds__(256) void k_txtpos(const float* __restrict__ txt,
                                                const float* __restrict__ vm,
                                                float* __restrict__ tn,
                                                float* __restrict__ posbuf) {
  __shared__ float s4[4];
  const int a = blockIdx.x, tid = threadIdx.x;
  float x0 = txt[a * kD + tid], x1 = txt[a * kD + tid + 256];
  float nn = breduce(x0 * x0 + x1 * x1, s4);
  float n = fmaxf(sqrtf(nn), 1e-12f);
  float y0 = x0 / n, y1 = x1 / n;
  tn[a * kD + tid] = y0;
  tn[a * kD + tid + 256] = y1;
  float d = y0 * vm[a * kD + tid] + y1 * vm[a * kD + tid + 256];
  float dot = breduce(d, s4);
  if (tid == 0) posbuf[a] = dot;
}

// All-pairs dot(tn_a, vm_b): accumulate sum(dot) and sum(dot^2) in f64.
__global__ __launch_bounds__(256) void k_egemm(const float* __restrict__ A,
                                               const float* __restrict__ Bm,
                                               double* __restrict__ acc) {
  __shared__ float As[64][65];
  __shared__ float Bs[64][65];
  __shared__ double rs[8];
  const int tid = threadIdx.x;
  const int aBase = blockIdx.y * 64;
  const int bBase = blockIdx.x * 64;
  const int tx = tid & 15, ty = tid >> 4;
  float c[4][4];
#pragma unroll
  for (int i = 0; i < 4; ++i)
#pragma unroll
    for (int j = 0; j < 4; ++j) c[i][j] = 0.f;

  for (int kk = 0; kk < kD; kk += 64) {
#pragma unroll
    for (int l = 0; l < 16; ++l) {
      int li = l * 256 + tid;
      int row = li >> 6, col = li & 63;
      As[row][col] = A[(aBase + row) * kD + kk + col];
      Bs[row][col] = Bm[(bBase + row) * kD + kk + col];
    }
    __syncthreads();
#pragma unroll 4
    for (int k = 0; k < 64; ++k) {
      float a0 = As[ty][k], a1 = As[ty + 16][k], a2 = As[ty + 32][k], a3 = As[ty + 48][k];
      float b0 = Bs[tx][k], b1 = Bs[tx + 16][k], b2 = Bs[tx + 32][k], b3 = Bs[tx + 48][k];
      c[0][0] = fmaf(a0, b0, c[0][0]); c[0][1] = fmaf(a0, b1, c[0][1]);
      c[0][2] = fmaf(a0, b2, c[0][2]); c[0][3] = fmaf(a0, b3, c[0][3]);
      c[1][0] = fmaf(a1, b0, c[1][0]); c[1][1] = fmaf(a1, b1, c[1][1]);
      c[1][2] = fmaf(a1, b2, c[1][2]); c[1][3] = fmaf(a1, b3, c[1][3]);
      c[2][0] = fmaf(a2, b0, c[2][0]); c[2][1] = fmaf(a2, b1, c[2][1]);
      c[2][2] = fmaf(a2, b2, c[2][2]); c[2][3] = fmaf(a2, b3, c[2][3]);
      c[3][0] = fmaf(a3, b0, c[3][0]); c[3][1] = fmaf(a3, b1, c[3][1]);
      c[3][2] = fmaf(a3, b2, c[3][2]); c[3][3] = fmaf(a3, b3, c[3][3]);
    }
    __syncthreads();
  }
  double s1 = 0.0, s2 = 0.0;
#pragma unroll
  for (int i = 0; i < 4; ++i)
#pragma unroll
    for (int j = 0; j < 4; ++j) {
      double cd = (double)c[i][j];
      s1 += cd;
      s2 += cd * cd;
    }
#pragma unroll
  for (int o = 32; o; o >>= 1) {
    s1 += __shfl_xor(s1, o);
    s2 += __shfl_xor(s2, o);
  }
  const int wid = tid >> 6;
  if ((tid & 63) == 0) { rs[wid] = s1; rs[wid + 4] = s2; }
  __syncthreads();
  if (tid == 0) {
    atomicAdd(&acc[0], rs[0] + rs[1] + rs[2] + rs[3]);
    atomicAdd(&acc[1], rs[4] + rs[5] + rs[6] + rs[7]);
  }
}

// ---------------- fused 30-step Langevin MCMC + final energy ----------------
// 512 threads/block, ONE element per thread (8 waves/block -> 32 waves/CU,
// double the TLP of the 256-thread version; per-thread serial chains halve).
// One fused reduction phase/step: 25 scalars via 32-lane ds_swizzle
// butterflies -> part[16][26] -> tid<25 combine, 2 barriers per step.
__global__ __launch_bounds__(512) void k_mcmc(const float* __restrict__ vinit,
                                              const float* __restrict__ tinit,
                                              float* __restrict__ esbuf,
                                              KeyChain K) {
  __shared__ float part[16][26];
  __shared__ float tot[26];
  const int a = blockIdx.x, tid = threadIdx.x;   // tid = element index d
  const uint32_t vbase = (uint32_t)a * (uint32_t)(kF * kD) + (uint32_t)tid;
  const uint32_t tbase = (uint32_t)a * (uint32_t)kD + (uint32_t)tid;
  float v0[kF];
#pragma unroll
  for (int f = 0; f < kF; ++f)
    v0[f] = 2.0f * vinit[vbase + f * kD] - 1.0f;
  float t0 = 2.0f * tinit[tbase] - 1.0f;

  const float CZ = 0.0070710678118654755f;  // 0.005 * sqrt(2)

  for (int j = 0; j <= 30; ++j) {
    // ---- fused reduction: tot[0]=t.t, tot[1+f]=v_f.v_f, tot[13+f]=v_f.t
    {
      float r = swz_add(t0 * t0);
      if ((tid & 31) == 0) part[tid >> 5][0] = r;
    }
#pragma unroll
    for (int f = 0; f < kF; ++f) {
      float rv = swz_add(v0[f] * v0[f]);
      float rt = swz_add(v0[f] * t0);
      if ((tid & 31) == 0) {
        part[tid >> 5][1 + f] = rv;
        part[tid >> 5][13 + f] = rt;
      }
    }
    __syncthreads();
    if (tid < 25) {
      float s = 0.f;
#pragma unroll
      for (int r = 0; r < 16; ++r) s += part[r][tid];
      tot[tid] = s;
    }
    __syncthreads();

    float minv = rsq_nr(tot[0]);   // 1/||t||

    if (j == 30) {                 // final energy_diag from the same scalars
      float se = 0.f;
#pragma unroll
      for (int f = 0; f < kF; ++f)
        se += tot[13 + f] * rsq_nr(tot[1 + f]) * minv;
      if (tid == 0) esbuf[a] = -se * (1.0f / 12.0f);
      break;
    }

    const uint32_t kv0 = K.k[4 * j + 0], kv1 = K.k[4 * j + 1];
    const uint32_t kt0 = K.k[4 * j + 2], kt1 = K.k[4 * j + 3];
    const uint32_t ksv = kv0 ^ kv1 ^ 0x1BD11BDAu;
    const uint32_t kst = kt0 ^ kt1 ^ 0x1BD11BDAu;
    float w0 = t0 * minv;
    float q0 = 0.f, qw = 0.f;
#pragma unroll
    for (int f = 0; f < kF; ++f) {
      float ninv = rsq_nr(tot[1 + f]);         // 1/||v_f||
      float s = tot[13 + f] * ninv * minv;     // u_f . w
      qw += s;
      float u0 = v0[f] * ninv;
      q0 += u0;
      float h = ninv * (0.01f / 12.0f);        // -0.01 * cf * ninv, cf=-1/12
      float p0 = normpx(rbits0(kv0, kv1, ksv, vbase + (uint32_t)(f * kD)));
      v0[f] = fmaf(CZ, p0, fmaf(h, fmaf(-s, u0, w0), v0[f]));
    }
    q0 *= (1.0f / 12.0f); qw *= (1.0f / 12.0f);
    float ht = 0.01f * minv;
    float p0 = normpx(rbits0(kt0, kt1, kst, tbase));
    t0 = fmaf(CZ, p0, fmaf(ht, fmaf(-qw, w0, q0), t0));
  }
}

// ---------------- final reduction + loss combine ----------------
__global__ __launch_bounds__(256) void k_fin(const double* __restrict__ acc,
                                             const float* __restrict__ posbuf,
                                             const float* __restrict__ esbuf,
                                             float* __restrict__ out) {
  __shared__ double sd[4][4];
  const int tid = threadIdx.x;
  double pd = 0, pd2 = 0, pe = 0, pe2 = 0;
  for (int i = tid; i < kB; i += 256) {
    double d = (double)posbuf[i];
    double e = (double)esbuf[i];
    pd += d; pd2 += d * d;
    pe += e; pe2 += e * e;
  }
#pragma unroll
  for (int o = 32; o; o >>= 1) {
    pd += __shfl_xor(pd, o);  pd2 += __shfl_xor(pd2, o);
    pe += __shfl_xor(pe, o);  pe2 += __shfl_xor(pe2, o);
  }
  const int w = tid >> 6;
  if ((tid & 63) == 0) { sd[w][0] = pd; sd[w][1] = pd2; sd[w][2] = pe; sd[w][3] = pe2; }
  __syncthreads();
  if (tid == 0) {
    double sumdot  = sd[0][0] + sd[1][0] + sd[2][0] + sd[3][0];
    double sumdot2 = sd[0][1] + sd[1][1] + sd[2][1] + sd[3][1];
    double es      = sd[0][2] + sd[1][2] + sd[2][2] + sd[3][2];
    double es2     = sd[0][3] + sd[1][3] + sd[2][3] + sd[3][3];
    double S1 = acc[0], S2 = acc[1];
    const double nn = 1024.0 * 1023.0;
    double pos_mean = -sumdot / 1024.0;       // mean of E_aa = -dot
    double neg_mean = (-S1 + sumdot) / nn;    // (E.sum - pos.sum)/nn
    double pos_sq   = sumdot2 / 1024.0;
    double neg_sq   = (S2 - sumdot2) / nn;
    double loss1 = pos_mean - neg_mean + 0.001 * (pos_sq + neg_sq);
    double loss2 = pos_mean - es / 1024.0 + 0.001 * (pos_sq + es2 / 1024.0);
    out[0] = (float)(0.5 * (loss1 + loss2));
  }
}

}  // namespace

extern "C" void kernel_launch(void* const* d_in, const int* in_sizes, int n_in,
                              void* d_out, int out_size, void* d_ws, size_t ws_size,
                              hipStream_t stream) {
  (void)in_sizes; (void)n_in; (void)out_size; (void)ws_size;
  const float* vid   = (const float*)d_in[0];
  const float* txt   = (const float*)d_in[1];
  const float* vinit = (const float*)d_in[2];
  const float* tinit = (const float*)d_in[3];
  float* out = (float*)d_out;

  char* ws = (char*)d_ws;
  double* acc   = (double*)ws;                 // 2 f64 accumulators
  float* posbuf = (float*)(ws + 256);          // [1024]
  float* esbuf  = posbuf + kB;                 // [1024]
  float* tn     = esbuf + kB;                  // [1024,512]
  float* vm     = tn + kNT;                    // [1024,512]

  hipMemsetAsync(acc, 0, 64, stream);

  // loss1 path
  k_vidmean<<<kB, 256, 0, stream>>>(vid, vm);
  k_txtpos<<<kB, 256, 0, stream>>>(txt, vm, tn, posbuf);
  k_egemm<<<dim3(16, 16), 256, 0, stream>>>(tn, vm, acc);

  // Host-side key chain, jax_threefry_partitionable=True semantics:
  //   keys = split(key(42), 30):      key_j  = tf((0,42), hi=0, lo=j)   (both words)
  //   kv, kt = split(key_j):          kv = tf(key_j, 0, 0), kt = tf(key_j, 0, 1)
  KeyChain K;
  for (uint32_t j = 0; j < 30; ++j) {
    uint32_t s0, s1, kv0, kv1, kt0, kt1;
    tf2x32(0u, 42u, 0u, j, s0, s1);
    tf2x32(s0, s1, 0u, 0u, kv0, kv1);
    tf2x32(s0, s1, 0u, 1u, kt0, kt1);
    K.k[4 * j + 0] = kv0; K.k[4 * j + 1] = kv1;
    K.k[4 * j + 2] = kt0; K.k[4 * j + 3] = kt1;
  }

  // fused MCMC + final per-sample energy
  k_mcmc<<<kB, 512, 0, stream>>>(vinit, tinit, esbuf, K);

  k_fin<<<1, 256, 0, stream>>>(acc, posbuf, esbuf, out);
}

// Round 7
// 564.886 us; speedup vs baseline: 1.0511x; 1.0511x over previous
//
#include <hip/hip_runtime.h>
#include <cstdint>

namespace {

constexpr int kB = 1024;
constexpr int kF = 12;
constexpr int kD = 512;
constexpr int kNT = kB * kD;        // 524288

// ---------------- threefry2x32 (exact JAX semantics) ----------------
#define TF_ROUND(r) { x0 += x1; x1 = (x1 << (r)) | (x1 >> (32 - (r))); x1 ^= x0; }

__host__ __device__ inline void tf2x32(uint32_t k0, uint32_t k1,
                                       uint32_t c0, uint32_t c1,
                                       uint32_t& o0, uint32_t& o1) {
  uint32_t ks2 = k0 ^ k1 ^ 0x1BD11BDAu;
  uint32_t x0 = c0 + k0;
  uint32_t x1 = c1 + k1;
  TF_ROUND(13) TF_ROUND(15) TF_ROUND(26) TF_ROUND(6)
  x0 += k1;  x1 += ks2 + 1u;
  TF_ROUND(17) TF_ROUND(29) TF_ROUND(16) TF_ROUND(24)
  x0 += ks2; x1 += k0 + 2u;
  TF_ROUND(13) TF_ROUND(15) TF_ROUND(26) TF_ROUND(6)
  x0 += k0;  x1 += k1 + 3u;
  TF_ROUND(17) TF_ROUND(29) TF_ROUND(16) TF_ROUND(24)
  x0 += k1;  x1 += ks2 + 4u;
  TF_ROUND(13) TF_ROUND(15) TF_ROUND(26) TF_ROUND(6)
  x0 += ks2; x1 += k0 + 5u;
  o0 = x0; o1 = x1;
}

// Device cipher specialized for counter (0, i). Rotates forced to a single
// v_alignbit_b32 each: rotl(x,r) == alignbit(x, x, 32-r) (rotate-right by
// 32-r of the doubled word) — bit-identical, guaranteed 1 inst.
// Returns x0 ^ x1 (JAX partitionable random_bits word).
__device__ __forceinline__ uint32_t rbits0(uint32_t k0, uint32_t k1,
                                           uint32_t ks2, uint32_t i) {
#define RR(r) { x0 += x1; \
  x1 = __builtin_amdgcn_alignbit(x1, x1, 32u - (r)); x1 ^= x0; }
  uint32_t x0 = k0;
  uint32_t x1 = i + k1;
  RR(13) RR(15) RR(26) RR(6)
  x0 += k1;  x1 += ks2 + 1u;
  RR(17) RR(29) RR(16) RR(24)
  x0 += ks2; x1 += k0 + 2u;
  RR(13) RR(15) RR(26) RR(6)
  x0 += k0;  x1 += k1 + 3u;
  RR(17) RR(29) RR(16) RR(24)
  x0 += k1;  x1 += ks2 + 4u;
  RR(13) RR(15) RR(26) RR(6)
  x0 += ks2; x1 += k0 + 5u;
  return x0 ^ x1;
#undef RR
}

// ---------------- fast HW transcendentals ----------------
__device__ __forceinline__ float fast_log2(float x) {
#if __has_builtin(__builtin_amdgcn_logf)
  return __builtin_amdgcn_logf(x);
#else
  return __log2f(x);
#endif
}

__device__ __forceinline__ float fast_sqrt(float x) {
#if __has_builtin(__builtin_amdgcn_sqrtf)
  return __builtin_amdgcn_sqrtf(x);
#else
  return sqrtf(x);
#endif
}

// 1/sqrt(x) via v_rsq + one Newton step (rel err ~1e-7)
__device__ __forceinline__ float rsq_nr(float x) {
#if __has_builtin(__builtin_amdgcn_rsqf)
  float r = __builtin_amdgcn_rsqf(x);
#else
  float r = 1.0f / sqrtf(x);
#endif
  float h = 0.5f * x;
  return r * (1.5f - h * r * r);
}

// p*u where sqrt(2)*p*u = sqrt(2)*erfinv(u), u from JAX-normal bit recipe.
// Head trimmed: u = fma(cvt(bits>>9), 2^-22, lo) is bit-identical to the
// (|0x3F800000)-1.0, *2+lo, fmax sequence. Tail poly behind wave-uniform
// branch (taken ~20% of wave-calls).
__device__ __forceinline__ float normpx(uint32_t bits) {
  const float lo = __uint_as_float(0xBF7FFFFFu);                 // -0.99999994
  float u = fmaf((float)(bits >> 9), 0x1p-22f, lo);
  float y = fmaf(-u, u, 1.0f);                                   // 1-u^2
  float w = -0.69314718055994531f * fast_log2(y);                // -ln(1-u^2)
  float wa = w - 2.5f;
  float p = 2.81022636e-08f;
  p = fmaf(p, wa, 3.43273939e-07f);
  p = fmaf(p, wa, -3.5233877e-06f);
  p = fmaf(p, wa, -4.39150654e-06f);
  p = fmaf(p, wa, 0.00021858087f);
  p = fmaf(p, wa, -0.00125372503f);
  p = fmaf(p, wa, -0.00417768164f);
  p = fmaf(p, wa, 0.246640727f);
  p = fmaf(p, wa, 1.50140941f);
  if (__builtin_expect(__any(w >= 5.0f), 0)) {
    float wb = fast_sqrt(w) - 3.0f;
    float pb = -0.000200214257f;
    pb = fmaf(pb, wb, 0.000100950558f);
    pb = fmaf(pb, wb, 0.00134934322f);
    pb = fmaf(pb, wb, -0.00367342844f);
    pb = fmaf(pb, wb, 0.00573950773f);
    pb = fmaf(pb, wb, -0.0076224613f);
    pb = fmaf(pb, wb, 0.00943887047f);
    pb = fmaf(pb, wb, 1.00167406f);
    pb = fmaf(pb, wb, 2.83297682f);
    p = (w < 5.0f) ? p : pb;
  }
  return p * u;
}

// 5-level xor-butterfly within 32-lane groups via raw ds_swizzle (BitMode:
// offset = (xor_mask<<10) | 0x1F). Zero VALU for the lane move.
__device__ __forceinline__ float swz_add(float x) {
  x += __int_as_float(__builtin_amdgcn_ds_swizzle(__float_as_int(x), 0x041F));
  x += __int_as_float(__builtin_amdgcn_ds_swizzle(__float_as_int(x), 0x081F));
  x += __int_as_float(__builtin_amdgcn_ds_swizzle(__float_as_int(x), 0x101F));
  x += __int_as_float(__builtin_amdgcn_ds_swizzle(__float_as_int(x), 0x201F));
  x += __int_as_float(__builtin_amdgcn_ds_swizzle(__float_as_int(x), 0x401F));
  return x;
}

// ---------------- block reductions for loss1 kernels ----------------
__device__ __forceinline__ float breduce(float x, float* s4) {
#pragma unroll
  for (int o = 32; o; o >>= 1) x += __shfl_xor(x, o);
  const int w = threadIdx.x >> 6;
  if ((threadIdx.x & 63) == 0) s4[w] = x;
  __syncthreads();
  float r = s4[0] + s4[1] + s4[2] + s4[3];
  __syncthreads();
  return r;
}

struct KeyChain { uint32_t k[120]; };  // per step: kv0,kv1,kt0,kt1

// ---------------- loss1 kernels ----------------
__global__ __launch_bounds__(256) void k_vidmean(const float* __restrict__ vid,
                                                 float* __restrict__ vm) {
  __shared__ float s4[4];
  const int b = blockIdx.x, tid = threadIdx.x;
  float a0 = 0.f, a1 = 0.f;
  for (int f = 0; f < kF; ++f) {
    const float* row = vid + (b * kF + f) * kD;
    float x0 = row[tid], x1 = row[tid + 256];
    float nn = breduce(x0 * x0 + x1 * x1, s4);
    float n = fmaxf(sqrtf(nn), 1e-12f);
    a0 += x0 / n;
    a1 += x1 / n;
  }
  vm[b * kD + tid] = a0 / 12.0f;
  vm[b * kD + tid + 256] = a1 / 12.0f;
}

// txt row-normalize + paired diag dot with vm (fused k_txtnorm + k_pos)
__global__ __launch_bounds__(256) void k_txtpos(const float* __restrict__ txt,
                                                const float* __restrict__ vm,
                                                float* __restrict__ tn,
                                                float* __restrict__ posbuf) {
  __shared__ float s4[4];
  const int a = blockIdx.x, tid = threadIdx.x;
  float x0 = txt[a * kD + tid], x1 = txt[a * kD + tid + 256];
  float nn = breduce(x0 * x0 + x1 * x1, s4);
  float n = fmaxf(sqrtf(nn), 1e-12f);
  float y0 = x0 / n, y1 = x1 / n;
  tn[a * kD + tid] = y0;
  tn[a * kD + tid + 256] = y1;
  float d = y0 * vm[a * kD + tid] + y1 * vm[a * kD + tid + 256];
  float dot = breduce(d, s4);
  if (tid == 0) posbuf[a] = dot;
}

// All-pairs dot(tn_a, vm_b): accumulate sum(dot) and sum(dot^2) in f64.
__global__ __launch_bounds__(256) void k_egemm(const float* __restrict__ A,
                                               const float* __restrict__ Bm,
                                               double* __restrict__ acc) {
  __shared__ float As[64][65];
  __shared__ float Bs[64][65];
  __shared__ double rs[8];
  const int tid = threadIdx.x;
  const int aBase = blockIdx.y * 64;
  const int bBase = blockIdx.x * 64;
  const int tx = tid & 15, ty = tid >> 4;
  float c[4][4];
#pragma unroll
  for (int i = 0; i < 4; ++i)
#pragma unroll
    for (int j = 0; j < 4; ++j) c[i][j] = 0.f;

  for (int kk = 0; kk < kD; kk += 64) {
#pragma unroll
    for (int l = 0; l < 16; ++l) {
      int li = l * 256 + tid;
      int row = li >> 6, col = li & 63;
      As[row][col] = A[(aBase + row) * kD + kk + col];
      Bs[row][col] = Bm[(bBase + row) * kD + kk + col];
    }
    __syncthreads();
#pragma unroll 4
    for (int k = 0; k < 64; ++k) {
      float a0 = As[ty][k], a1 = As[ty + 16][k], a2 = As[ty + 32][k], a3 = As[ty + 48][k];
      float b0 = Bs[tx][k], b1 = Bs[tx + 16][k], b2 = Bs[tx + 32][k], b3 = Bs[tx + 48][k];
      c[0][0] = fmaf(a0, b0, c[0][0]); c[0][1] = fmaf(a0, b1, c[0][1]);
      c[0][2] = fmaf(a0, b2, c[0][2]); c[0][3] = fmaf(a0, b3, c[0][3]);
      c[1][0] = fmaf(a1, b0, c[1][0]); c[1][1] = fmaf(a1, b1, c[1][1]);
      c[1][2] = fmaf(a1, b2, c[1][2]); c[1][3] = fmaf(a1, b3, c[1][3]);
      c[2][0] = fmaf(a2, b0, c[2][0]); c[2][1] = fmaf(a2, b1, c[2][1]);
      c[2][2] = fmaf(a2, b2, c[2][2]); c[2][3] = fmaf(a2, b3, c[2][3]);
      c[3][0] = fmaf(a3, b0, c[3][0]); c[3][1] = fmaf(a3, b1, c[3][1]);
      c[3][2] = fmaf(a3, b2, c[3][2]); c[3][3] = fmaf(a3, b3, c[3][3]);
    }
    __syncthreads();
  }
  double s1 = 0.0, s2 = 0.0;
#pragma unroll
  for (int i = 0; i < 4; ++i)
#pragma unroll
    for (int j = 0; j < 4; ++j) {
      double cd = (double)c[i][j];
      s1 += cd;
      s2 += cd * cd;
    }
#pragma unroll
  for (int o = 32; o; o >>= 1) {
    s1 += __shfl_xor(s1, o);
    s2 += __shfl_xor(s2, o);
  }
  const int wid = tid >> 6;
  if ((tid & 63) == 0) { rs[wid] = s1; rs[wid + 4] = s2; }
  __syncthreads();
  if (tid == 0) {
    atomicAdd(&acc[0], rs[0] + rs[1] + rs[2] + rs[3]);
    atomicAdd(&acc[1], rs[4] + rs[5] + rs[6] + rs[7]);
  }
}

// ---------------- fused 30-step Langevin MCMC + final energy ----------------
// R5 structure (best): 256 threads, 2 elems/thread, 4 waves/block.
// One fused reduction phase/step: 25 scalars via 32-lane ds_swizzle
// butterflies -> part[8][26] -> tid<25 combine, 2 barriers per step.
__global__ __launch_bounds__(256) void k_mcmc(const float* __restrict__ vinit,
                                              const float* __restrict__ tinit,
                                              float* __restrict__ esbuf,
                                              KeyChain K) {
  __shared__ float part[8][26];
  __shared__ float tot[26];
  const int a = blockIdx.x, tid = threadIdx.x;
  const uint32_t vbase = (uint32_t)a * (uint32_t)(kF * kD) + (uint32_t)tid;
  const uint32_t tbase = (uint32_t)a * (uint32_t)kD + (uint32_t)tid;
  float v0[kF], v1[kF];
#pragma unroll
  for (int f = 0; f < kF; ++f) {
    v0[f] = 2.0f * vinit[vbase + f * kD] - 1.0f;
    v1[f] = 2.0f * vinit[vbase + f * kD + 256] - 1.0f;
  }
  float t0 = 2.0f * tinit[tbase] - 1.0f;
  float t1 = 2.0f * tinit[tbase + 256] - 1.0f;

  const float CZ = 0.0070710678118654755f;  // 0.005 * sqrt(2)

  for (int j = 0; j <= 30; ++j) {
    // ---- fused reduction: tot[0]=t.t, tot[1+f]=v_f.v_f, tot[13+f]=v_f.t
    {
      float r = swz_add(t0 * t0 + t1 * t1);
      if ((tid & 31) == 0) part[tid >> 5][0] = r;
    }
#pragma unroll
    for (int f = 0; f < kF; ++f) {
      float rv = swz_add(v0[f] * v0[f] + v1[f] * v1[f]);
      float rt = swz_add(v0[f] * t0 + v1[f] * t1);
      if ((tid & 31) == 0) {
        part[tid >> 5][1 + f] = rv;
        part[tid >> 5][13 + f] = rt;
      }
    }
    __syncthreads();
    if (tid < 25) {
      float s = 0.f;
#pragma unroll
      for (int r = 0; r < 8; ++r) s += part[r][tid];
      tot[tid] = s;
    }
    __syncthreads();

    float minv = rsq_nr(tot[0]);   // 1/||t||

    if (j == 30) {                 // final energy_diag from the same scalars
      float se = 0.f;
#pragma unroll
      for (int f = 0; f < kF; ++f)
        se += tot[13 + f] * rsq_nr(tot[1 + f]) * minv;
      if (tid == 0) esbuf[a] = -se * (1.0f / 12.0f);
      break;
    }

    const uint32_t kv0 = K.k[4 * j + 0], kv1 = K.k[4 * j + 1];
    const uint32_t kt0 = K.k[4 * j + 2], kt1 = K.k[4 * j + 3];
    const uint32_t ksv = kv0 ^ kv1 ^ 0x1BD11BDAu;
    const uint32_t kst = kt0 ^ kt1 ^ 0x1BD11BDAu;
    float w0 = t0 * minv, w1 = t1 * minv;
    float q0 = 0.f, q1 = 0.f, qw = 0.f;
#pragma unroll
    for (int f = 0; f < kF; ++f) {
      float ninv = rsq_nr(tot[1 + f]);         // 1/||v_f||
      float s = tot[13 + f] * ninv * minv;     // u_f . w
      qw += s;
      float u0 = v0[f] * ninv, u1 = v1[f] * ninv;
      q0 += u0; q1 += u1;
      float h = ninv * (0.01f / 12.0f);        // -0.01 * cf * ninv, cf=-1/12
      const uint32_t iv = vbase + (uint32_t)(f * kD);
      float p0 = normpx(rbits0(kv0, kv1, ksv, iv));
      float p1 = normpx(rbits0(kv0, kv1, ksv, iv + 256u));
      v0[f] = fmaf(CZ, p0, fmaf(h, fmaf(-s, u0, w0), v0[f]));
      v1[f] = fmaf(CZ, p1, fmaf(h, fmaf(-s, u1, w1), v1[f]));
    }
    q0 *= (1.0f / 12.0f); q1 *= (1.0f / 12.0f); qw *= (1.0f / 12.0f);
    float ht = 0.01f * minv;
    float p0 = normpx(rbits0(kt0, kt1, kst, tbase));
    float p1 = normpx(rbits0(kt0, kt1, kst, tbase + 256u));
    t0 = fmaf(CZ, p0, fmaf(ht, fmaf(-qw, w0, q0), t0));
    t1 = fmaf(CZ, p1, fmaf(ht, fmaf(-qw, w1, q1), t1));
  }
}

// ---------------- final reduction + loss combine ----------------
__global__ __launch_bounds__(256) void k_fin(const double* __restrict__ acc,
                                             const float* __restrict__ posbuf,
                                             const float* __restrict__ esbuf,
                                             float* __restrict__ out) {
  __shared__ double sd[4][4];
  const int tid = threadIdx.x;
  double pd = 0, pd2 = 0, pe = 0, pe2 = 0;
  for (int i = tid; i < kB; i += 256) {
    double d = (double)posbuf[i];
    double e = (double)esbuf[i];
    pd += d; pd2 += d * d;
    pe += e; pe2 += e * e;
  }
#pragma unroll
  for (int o = 32; o; o >>= 1) {
    pd += __shfl_xor(pd, o);  pd2 += __shfl_xor(pd2, o);
    pe += __shfl_xor(pe, o);  pe2 += __shfl_xor(pe2, o);
  }
  const int w = tid >> 6;
  if ((tid & 63) == 0) { sd[w][0] = pd; sd[w][1] = pd2; sd[w][2] = pe; sd[w][3] = pe2; }
  __syncthreads();
  if (tid == 0) {
    double sumdot  = sd[0][0] + sd[1][0] + sd[2][0] + sd[3][0];
    double sumdot2 = sd[0][1] + sd[1][1] + sd[2][1] + sd[3][1];
    double es      = sd[0][2] + sd[1][2] + sd[2][2] + sd[3][2];
    double es2     = sd[0][3] + sd[1][3] + sd[2][3] + sd[3][3];
    double S1 = acc[0], S2 = acc[1];
    const double nn = 1024.0 * 1023.0;
    double pos_mean = -sumdot / 1024.0;       // mean of E_aa = -dot
    double neg_mean = (-S1 + sumdot) / nn;    // (E.sum - pos.sum)/nn
    double pos_sq   = sumdot2 / 1024.0;
    double neg_sq   = (S2 - sumdot2) / nn;
    double loss1 = pos_mean - neg_mean + 0.001 * (pos_sq + neg_sq);
    double loss2 = pos_mean - es / 1024.0 + 0.001 * (pos_sq + es2 / 1024.0);
    out[0] = (float)(0.5 * (loss1 + loss2));
  }
}

}  // namespace

extern "C" void kernel_launch(void* const* d_in, const int* in_sizes, int n_in,
                              void* d_out, int out_size, void* d_ws, size_t ws_size,
                              hipStream_t stream) {
  (void)in_sizes; (void)n_in; (void)out_size; (void)ws_size;
  const float* vid   = (const float*)d_in[0];
  const float* txt   = (const float*)d_in[1];
  const float* vinit = (const float*)d_in[2];
  const float* tinit = (const float*)d_in[3];
  float* out = (float*)d_out;

  char* ws = (char*)d_ws;
  double* acc   = (double*)ws;                 // 2 f64 accumulators
  float* posbuf = (float*)(ws + 256);          // [1024]
  float* esbuf  = posbuf + kB;                 // [1024]
  float* tn     = esbuf + kB;                  // [1024,512]
  float* vm     = tn + kNT;                    // [1024,512]

  hipMemsetAsync(acc, 0, 64, stream);

  // loss1 path
  k_vidmean<<<kB, 256, 0, stream>>>(vid, vm);
  k_txtpos<<<kB, 256, 0, stream>>>(txt, vm, tn, posbuf);
  k_egemm<<<dim3(16, 16), 256, 0, stream>>>(tn, vm, acc);

  // Host-side key chain, jax_threefry_partitionable=True semantics:
  //   keys = split(key(42), 30):      key_j  = tf((0,42), hi=0, lo=j)   (both words)
  //   kv, kt = split(key_j):          kv = tf(key_j, 0, 0), kt = tf(key_j, 0, 1)
  KeyChain K;
  for (uint32_t j = 0; j < 30; ++j) {
    uint32_t s0, s1, kv0, kv1, kt0, kt1;
    tf2x32(0u, 42u, 0u, j, s0, s1);
    tf2x32(s0, s1, 0u, 0u, kv0, kv1);
    tf2x32(s0, s1, 0u, 1u, kt0, kt1);
    K.k[4 * j + 0] = kv0; K.k[4 * j + 1] = kv1;
    K.k[4 * j + 2] = kt0; K.k[4 * j + 3] = kt1;
  }

  // fused MCMC + final per-sample energy
  k_mcmc<<<kB, 256, 0, stream>>>(vinit, tinit, esbuf, K);

  k_fin<<<1, 256, 0, stream>>>(acc, posbuf, esbuf, out);
}